// Round 6
// baseline (854.527 us; speedup 1.0000x reference)
//
#include <hip/hip_runtime.h>
#include <cstdint>

// ---------------------------------------------------------------------------
// Complex differential attention block, MI355X (gfx950).
// B=2,H=8,S=1024,D=384.  Rows = B*H*S = 16384.
// fp16 MFMA (16x16x32), fp32 accumulate.
// R5: R4 geometry (256x256 BK=64, 8 waves/512thr, 128KB LDS dbuf, T2 XOR
//     swizzle -> bank-conflict 0) with the K-loop changed to DEPTH-2
//     COUNTED-VMCNT: per epoch {vmcnt(8); barrier; compute buf[t]; barrier;
//     stage(t+2)->freed buf}.  stage(t+1) stays in flight across the whole
//     epoch; vmcnt never drains to 0 in the main loop (R2/R4 poison).
// R6: fix MODE_OUT launch arity (missing outp2=nullptr) — R5 was a compile
//     failure, theory untested.
// ---------------------------------------------------------------------------

typedef _Float16 f16;
typedef __attribute__((ext_vector_type(8))) _Float16 f16x8;
typedef __attribute__((ext_vector_type(4))) _Float16 f16x4;
typedef __attribute__((ext_vector_type(4))) float    f32x4;

#define NROW      16384L
#define HALF_OUT  6291456L               // NROW*384
#define SCALE_QK  0.05103103630798288f   // 384^-0.5
#define LAMBDA_INIT 0.35550906759096926f

__device__ __forceinline__ void gl2lds16(const void* g, void* l) {
  __builtin_amdgcn_global_load_lds(
      (const __attribute__((address_space(1))) void*)(uintptr_t)g,
      (__attribute__((address_space(3))) void*)(uint32_t)(uintptr_t)l,
      16, 0, 0);
}

struct PeTab { const float* p[6]; float sgn[6]; };

enum { MODE_PROJ = 0, MODE_VT = 1, MODE_OUT = 2, MODE_PV = 3 };

// ---------------------------------------------------------------------------
// Unified C[M,N] = A[M,K] @ W[N,K]^T.  512 thr (8 waves, 2Mx4N), tile
// 256x256, BK=64 epochs, 2 LDS buffers (128KB).  Depth-2 counted pipeline:
// 8 gl2lds/thread/epoch, vmcnt(8) keeps next epoch's loads in flight.
// LDS rows are 8 chunks of 16B; chunk swizzle: LDS (r, c) holds global
// (r, c^(r&7)) -- source pre-swizzle + read swizzle, linear gl2lds dest.
// Modes: PROJ (f16 out + bias + pe), VT (Vt[bh][n][s] out), OUT (fp32
// planar), PV (A = stacked P1/P2 rows per bh, out O1/O2).
// Grid (1D, XCD-major):
//  PROJ/VT/OUT: grid = 8*8*gx; xcd=bid&7, per=bid>>3,
//               row_t = xcd*8+per/gx (M=16384), col_t = per%gx.
//  PV:          grid = 384; mt_g = xcd*16+per/3 (0..127), nt = per%3;
//               bh = mt_g>>3, mrow = (mt_g&7)*256 in [0,2048).
// ---------------------------------------------------------------------------
template <int MODE>
__launch_bounds__(512, 2)
__global__ void gemm256(const f16* __restrict__ A, int lda,
                        const f16* __restrict__ W, int ldw,
                        const float* __restrict__ bias, PeTab pe,
                        void* __restrict__ outp, void* __restrict__ outp2,
                        int ldo, int K, int gx)
{
  __shared__ f16 As[2][256 * 64];
  __shared__ f16 Bs[2][256 * 64];
  const int t    = threadIdx.x;
  const int lane = t & 63;
  const int wave = t >> 6;
  const int bid  = blockIdx.x;
  const int xcd  = bid & 7;
  const int per  = bid >> 3;

  long row0, col0;
  const f16 *Ab, *Wb;
  int bh = 0;
  if (MODE == MODE_PV) {
    const int pd3 = per / 3;
    const int ntile = per - pd3 * 3;
    const int mt_g = xcd * 16 + pd3;          // 0..127
    bh   = mt_g >> 3;
    row0 = (long)(mt_g & 7) * 256;            // local row in [0,2048)
    col0 = (long)ntile * 256;
    Ab = A + ((long)(bh + (row0 >= 1024 ? 16 : 0)) << 20) + (row0 & 1023) * (long)lda;
    Wb = W + (long)bh * 768 * 1024 + col0 * (long)ldw;
  } else {
    row0 = (long)(xcd * 8 + per / gx) * 256;
    col0 = (long)(per % gx) * 256;
    Ab = A + row0 * (long)lda;
    Wb = W + col0 * (long)ldw;
  }

  const int wm = (wave >> 2) * 128;           // 2 M-groups
  const int wn = (wave & 3) * 64;             // 4 N-groups
  const int lm = lane & 15;
  const int l4 = lane >> 4;

  f32x4 acc[8][4] = {};

  // stage one BK=64 tile pair; 8 gl2lds/thread; linear LDS dest (lane*16B),
  // global source column chunk pre-swizzled: cg = cl ^ (r&7).
  auto stage = [&](int kk, int sub) {
#pragma unroll
    for (int p = 0; p < 4; ++p) {
      int sg = p * 512 + t;                   // 0..2047
      int r = sg >> 3, cl = sg & 7;
      int cg = cl ^ (r & 7);
      gl2lds16(Ab + (long)r * lda + kk + cg * 8, &As[sub][sg * 8]);
      gl2lds16(Wb + (long)r * ldw + kk + cg * 8, &Bs[sub][sg * 8]);
    }
  };

  const int NT = K >> 6;
  stage(0, 0);
  stage(64, 1);
  int cur = 0;
  for (int it = 0; it < NT; ++it) {
    // own stage(it) landed; stage(it+1)'s 8 loads stay in flight
    if (it + 1 < NT) asm volatile("s_waitcnt vmcnt(8)" ::: "memory");
    else             asm volatile("s_waitcnt vmcnt(0)" ::: "memory");
    __builtin_amdgcn_s_barrier();             // all waves' stage(it) visible
#pragma unroll
    for (int ks = 0; ks < 2; ++ks) {
      f16x8 bfr[4];
#pragma unroll
      for (int nt = 0; nt < 4; ++nt) {
        int rr = wn + nt * 16 + lm;
        bfr[nt] = *(const f16x8*)&Bs[cur][rr * 64 + (((ks * 4 + l4) ^ (rr & 7)) * 8)];
      }
#pragma unroll
      for (int mt = 0; mt < 8; ++mt) {
        int rr = wm + mt * 16 + lm;
        f16x8 afr = *(const f16x8*)&As[cur][rr * 64 + (((ks * 4 + l4) ^ (rr & 7)) * 8)];
#pragma unroll
        for (int nt = 0; nt < 4; ++nt)
          acc[mt][nt] = __builtin_amdgcn_mfma_f32_16x16x32_f16(afr, bfr[nt], acc[mt][nt], 0, 0, 0);
      }
    }
    __builtin_amdgcn_s_barrier();             // all reads of buf[cur] done
    if (it + 2 < NT) stage((it + 2) << 6, cur);   // refill freed buffer
    cur ^= 1;
  }

  const int lm4 = l4 * 4;
  const int ln  = lm;
#pragma unroll
  for (int mt = 0; mt < 8; ++mt) {
#pragma unroll
    for (int nt = 0; nt < 4; ++nt) {
      int col = (int)col0 + wn + nt * 16 + ln;
      if (MODE == MODE_VT) {
        long rowb = row0 + wm + mt * 16 + lm4;
        long vbh = rowb >> 10, sx = rowb & 1023;
        f16x4 v;
#pragma unroll
        for (int r = 0; r < 4; ++r) v[r] = (f16)(acc[mt][nt][r] + bias[col]);
        *(f16x4*)&((f16*)outp)[(vbh * 768 + col) * 1024 + sx] = v;   // Vt[bh][n][s]
      } else if (MODE == MODE_PV) {
#pragma unroll
        for (int r = 0; r < 4; ++r) {
          long grow = row0 + wm + mt * 16 + lm4 + r;   // 0..2047, uniform half
          f16 val = (f16)acc[mt][nt][r];
          if (grow < 1024) ((f16*)outp )[((long)bh * 1024 + grow)        * 768 + col] = val;
          else             ((f16*)outp2)[((long)bh * 1024 + grow - 1024) * 768 + col] = val;
        }
      } else {
#pragma unroll
        for (int r = 0; r < 4; ++r) {
          long row = row0 + wm + mt * 16 + lm4 + r;
          float c = acc[mt][nt][r] + bias[col];
          if (MODE == MODE_PROJ) {
            int s2 = col / 384;
            int d  = col - s2 * 384;
            const float* pp = pe.p[s2];
            if (pp) c += pe.sgn[s2] * pp[row * 384 + d];
            ((f16*)outp)[row * (long)ldo + col] = (f16)c;
          } else {  // MODE_OUT
            float* of = (float*)outp;
            if (col < 384) of[row * 384 + col] = c;
            else           of[HALF_OUT + row * 384 + (col - 384)] = c;
          }
        }
      }
    }
  }
}

// ---------------------------------------------------------------------------
// Score: for slab (w,bh): P[slab] rows = |s| * scale where
//   s_r[q,k] = [qr|qi] . Kc[k] over K=768           (plain GEMM)
//   s_i[q,k] = [qr|qi] . [-ki|kr] over K=768:
//     epoch kk<384:  acci += (-a) . Kc[:,kk+384..]  (window +384, neg A)
//     epoch kk>=384: acci += ( a) . Kc[:,kk-384..]  (window -384)
// Tile 256x128, 512 thr (8 waves 4Mx2N), BK=64, dual-B stage (A 64KB +
// B 32KB + C 32KB = 128KB), 64 MFMA/wave/epoch, 8 gl2lds/thread/epoch.
// Depth-2 counted pipeline, vmcnt(8).
// Grid 1024: xcd=bid&7, per=bid>>3 (0..127); slab = xcd*4+(per>>5) = w*16+bh;
// tile = per&31: row0=(tile>>3)*256, col0=(tile&7)*128.
// ---------------------------------------------------------------------------
__launch_bounds__(512, 2)
__global__ void score256(const f16* __restrict__ QG, const f16* __restrict__ Kc,
                         f16* __restrict__ P)
{
  __shared__ f16 As[2][256 * 64];
  __shared__ f16 Bs[2][128 * 64];
  __shared__ f16 Cs[2][128 * 64];
  const int t = threadIdx.x, lane = t & 63, wave = t >> 6;
  const int bid = blockIdx.x;
  const int xcd = bid & 7, per = bid >> 3;
  const int slab = xcd * 4 + (per >> 5);      // = w*16 + bh
  const int tile = per & 31;
  const int w = slab >> 4, bh = slab & 15;
  const long row0 = (long)(tile >> 3) * 256;
  const long col0 = (long)(tile & 7) * 128;
  const f16* Ab = QG + (long)bh * 1024 * 2304 + row0 * 2304 + w * 768;
  const f16* Bb = Kc + (long)bh * 1024 * 768 + col0 * 768;

  const int wm = (wave >> 1) * 64;            // 4 M-groups
  const int wn = (wave & 1) * 64;             // 2 N-groups
  const int lm = lane & 15, l4 = lane >> 4;

  f32x4 accr[4][4] = {}, acci[4][4] = {};

  auto stage = [&](int kk, int sub) {
    int kk2 = kk < 384 ? kk + 384 : kk - 384;
#pragma unroll
    for (int p = 0; p < 4; ++p) {
      int sg = p * 512 + t;
      int r = sg >> 3, cl = sg & 7, cg = cl ^ (r & 7);
      gl2lds16(Ab + (long)r * 2304 + kk + cg * 8, &As[sub][sg * 8]);
    }
#pragma unroll
    for (int p = 0; p < 2; ++p) {
      int sg = p * 512 + t;
      int r = sg >> 3, cl = sg & 7, cg = cl ^ (r & 7);
      gl2lds16(Bb + (long)r * 768 + kk  + cg * 8, &Bs[sub][sg * 8]);
      gl2lds16(Bb + (long)r * 768 + kk2 + cg * 8, &Cs[sub][sg * 8]);
    }
  };

  stage(0, 0);
  stage(64, 1);
  int cur = 0;
  for (int it = 0; it < 12; ++it) {
    if (it + 1 < 12) asm volatile("s_waitcnt vmcnt(8)" ::: "memory");
    else             asm volatile("s_waitcnt vmcnt(0)" ::: "memory");
    __builtin_amdgcn_s_barrier();
    const bool neg = (it < 6);                // kk<384 -> negate A for s_i
#pragma unroll
    for (int ks = 0; ks < 2; ++ks) {
      f16x8 bfr[4], cfr[4];
#pragma unroll
      for (int nt = 0; nt < 4; ++nt) {
        int rr = wn + nt * 16 + lm;
        int off = rr * 64 + (((ks * 4 + l4) ^ (rr & 7)) * 8);
        bfr[nt] = *(const f16x8*)&Bs[cur][off];
        cfr[nt] = *(const f16x8*)&Cs[cur][off];
      }
#pragma unroll
      for (int mt = 0; mt < 4; ++mt) {
        int rr = wm + mt * 16 + lm;
        f16x8 a  = *(const f16x8*)&As[cur][rr * 64 + (((ks * 4 + l4) ^ (rr & 7)) * 8)];
        f16x8 am = neg ? -a : a;
#pragma unroll
        for (int nt = 0; nt < 4; ++nt) {
          accr[mt][nt] = __builtin_amdgcn_mfma_f32_16x16x32_f16(a,  bfr[nt], accr[mt][nt], 0, 0, 0);
          acci[mt][nt] = __builtin_amdgcn_mfma_f32_16x16x32_f16(am, cfr[nt], acci[mt][nt], 0, 0, 0);
        }
      }
    }
    __builtin_amdgcn_s_barrier();
    if (it + 2 < 12) stage((it + 2) << 6, cur);
    cur ^= 1;
  }

  f16* Pz = P + ((long)slab << 20);
  const int lm4 = l4 * 4, ln = lm;
#pragma unroll
  for (int mt = 0; mt < 4; ++mt)
#pragma unroll
    for (int nt = 0; nt < 4; ++nt) {
      int col = (int)col0 + wn + nt * 16 + ln;
#pragma unroll
      for (int r = 0; r < 4; ++r) {
        long row = row0 + wm + mt * 16 + lm4 + r;
        float sr = accr[mt][nt][r], si = acci[mt][nt][r];
        float m = sqrtf(sr * sr + si * si + 1e-8f) * SCALE_QK;
        Pz[row * 1024 + col] = (f16)m;
      }
    }
}

// In-place row softmax over 1024 logits; 1 wave per row, 4 rows per block.
__global__ void softmax_kernel(f16* __restrict__ P)
{
  const long row = (long)blockIdx.x * 4 + (threadIdx.x >> 6);
  f16* p = P + row * 1024;
  const int lane = threadIdx.x & 63;
  f16x8 v0 = *(const f16x8*)(p + lane * 16);
  f16x8 v1 = *(const f16x8*)(p + lane * 16 + 8);
  float x[16];
#pragma unroll
  for (int i = 0; i < 8; ++i) { x[i] = (float)v0[i]; x[8 + i] = (float)v1[i]; }
  float m = x[0];
#pragma unroll
  for (int i = 1; i < 16; ++i) m = fmaxf(m, x[i]);
#pragma unroll
  for (int off = 1; off < 64; off <<= 1) m = fmaxf(m, __shfl_xor(m, off));
  float s = 0.f;
#pragma unroll
  for (int i = 0; i < 16; ++i) { x[i] = __expf(x[i] - m); s += x[i]; }
#pragma unroll
  for (int off = 1; off < 64; off <<= 1) s += __shfl_xor(s, off);
  float inv = 1.f / s;
  f16x8 o0, o1;
#pragma unroll
  for (int i = 0; i < 8; ++i) { o0[i] = (f16)(x[i] * inv); o1[i] = (f16)(x[8 + i] * inv); }
  *(f16x8*)(p + lane * 16)     = o0;
  *(f16x8*)(p + lane * 16 + 8) = o1;
}

// RMSNorm over cat(a1,a2) + lambda diff + complex gate -> Xatt fp16.
// G lives in QG cols 1536..2303.
__global__ void fuse_kernel(const f16* __restrict__ A1, const f16* __restrict__ A2,
                            const f16* __restrict__ QG, const float* __restrict__ subw,
                            const float* __restrict__ lamp, f16* __restrict__ Xatt)
{
  const long row = blockIdx.x;
  const int t = threadIdx.x, lane = t & 63, wv = t >> 6;
  const f16* a1 = A1 + row * 768;
  const f16* a2 = A2 + row * 768;
  const f16* g  = QG + row * 2304 + 1536;
  float a1r[3], a1i[3], a2r[3], a2i[3];
  float ss = 0.f;
#pragma unroll
  for (int q = 0; q < 3; ++q) {
    int d = t + q * 128;
    a1r[q] = (float)a1[d]; a1i[q] = (float)a1[d + 384];
    a2r[q] = (float)a2[d]; a2i[q] = (float)a2[d + 384];
    ss += a1r[q] * a1r[q] + a1i[q] * a1i[q] + a2r[q] * a2r[q] + a2i[q] * a2i[q];
  }
#pragma unroll
  for (int m = 1; m < 64; m <<= 1) ss += __shfl_xor(ss, m);
  __shared__ float part[2];
  if (lane == 0) part[wv] = ss;
  __syncthreads();
  float inv = rsqrtf((part[0] + part[1]) * (1.f / 768.f) + 1e-5f);
  float lam = lamp[0];
#pragma unroll
  for (int q = 0; q < 3; ++q) {
    int d = t + q * 128;
    float w1 = subw[d], w2 = subw[d + 384];
    float n1r = a1r[q] * inv * w1, n1i = a1i[q] * inv * w1;
    float n2r = a2r[q] * inv * w2, n2i = a2i[q] * inv * w2;
    float orr = n1r - lam * n2r, oii = n1i - lam * n2i;
    float gr = (float)g[d], gi = (float)g[d + 384];
    Xatt[row * 768 + d]       = (f16)(gr * orr - gi * oii);
    Xatt[row * 768 + d + 384] = (f16)(gr * oii + gi * orr);
  }
}

__global__ void lam_kernel(const float* lq1, const float* lk1,
                           const float* lq2, const float* lk2, float* out)
{
  const int t = threadIdx.x, lane = t & 63, wv = t >> 6;
  float s1 = 0.f, s2 = 0.f;
#pragma unroll
  for (int q = 0; q < 3; ++q) {
    int d = t + q * 128;
    s1 += lq1[d] * lk1[d];
    s2 += lq2[d] * lk2[d];
  }
#pragma unroll
  for (int m = 1; m < 64; m <<= 1) { s1 += __shfl_xor(s1, m); s2 += __shfl_xor(s2, m); }
  __shared__ float p1[2], p2[2];
  if (lane == 0) { p1[wv] = s1; p2[wv] = s2; }
  __syncthreads();
  if (t == 0) {
    float x = expf(p1[0] + p1[1]) - expf(p2[0] + p2[1]) + LAMBDA_INIT;
    out[0] = 1.f / (1.f + expf(-x));
  }
}

// X = [xr | xi] fp16, row-major [16384][768].  8 elements per thread.
__global__ void pack_x(const float* __restrict__ xr, const float* __restrict__ xi,
                       f16* __restrict__ X)
{
  long i = (long)blockIdx.x * 256 + threadIdx.x;   // < 16384*96
  long row = i / 96;
  int  rem = (int)(i - row * 96);
  int  c   = rem * 8;
  const float* src = (c < 384) ? (xr + row * 384 + c) : (xi + row * 384 + (c - 384));
  f16x8 o;
#pragma unroll
  for (int j = 0; j < 8; ++j) o[j] = (f16)src[j];
  *(f16x8*)&X[row * 768 + c] = o;
}

// Wq' [2304][768]: sections of 384 rows: 0:q1_r 1:q1_i 2:q2_r 3:q2_i 4:g_r 5:g_i
__global__ void pack_wq(const float* wq_r, const float* wq_i,
                        const float* wg_r, const float* wg_i,
                        const float* bq_r, const float* bq_i,
                        const float* bg_r, const float* bg_i,
                        f16* __restrict__ Wp, float* __restrict__ bp)
{
  long i = (long)blockIdx.x * 256 + threadIdx.x;   // < 2304*768
  int n = (int)(i / 768), e = (int)(i % 768);
  int s = n / 384, d = n - s * 384;
  int hb = (e >= 384);
  int ee = e - hb * 384;
  float v = 0.f, b = 0.f;
  switch (s) {
    case 0: v = hb ? -wq_i[d * 384 + ee]         :  wq_r[d * 384 + ee];         b = bq_r[d];       break;
    case 1: v = hb ?  wq_r[d * 384 + ee]         :  wq_i[d * 384 + ee];         b = bq_i[d];       break;
    case 2: v = hb ? -wq_i[(384 + d) * 384 + ee] :  wq_r[(384 + d) * 384 + ee]; b = bq_r[384 + d]; break;
    case 3: v = hb ?  wq_r[(384 + d) * 384 + ee] :  wq_i[(384 + d) * 384 + ee]; b = bq_i[384 + d]; break;
    case 4: v = hb ? -wg_i[d * 384 + ee]         :  wg_r[d * 384 + ee];         b = bg_r[d];       break;
    case 5: v = hb ?  wg_r[d * 384 + ee]         :  wg_i[d * 384 + ee];         b = bg_i[d];       break;
  }
  Wp[i] = (f16)v;
  if (e == 0) bp[n] = b;
}

// standard complex-linear pack: rows [o_r(384) | o_i(384)]
__global__ void pack_w_std(const float* wr, const float* wi,
                           const float* br, const float* bi,
                           f16* __restrict__ Wp, float* __restrict__ bp)
{
  long i = (long)blockIdx.x * 256 + threadIdx.x;   // < 768*768
  int n = (int)(i / 768), e = (int)(i % 768);
  int hb = (e >= 384);
  int ee = e - hb * 384;
  float v, b;
  if (n < 384) { v = hb ? -wi[n * 384 + ee] : wr[n * 384 + ee]; b = br[n]; }
  else { int d = n - 384; v = hb ? wr[d * 384 + ee] : wi[d * 384 + ee]; b = bi[d]; }
  Wp[i] = (f16)v;
  if (e == 0) bp[n] = b;
}

// ---------------------------------------------------------------------------
extern "C" void kernel_launch(void* const* d_in, const int* in_sizes, int n_in,
                              void* d_out, int out_size, void* d_ws, size_t ws_size,
                              hipStream_t stream)
{
  const float* q_r    = (const float*)d_in[0];
  const float* q_i    = (const float*)d_in[1];
  const float* k_r    = (const float*)d_in[2];
  const float* k_i    = (const float*)d_in[3];
  const float* v_r    = (const float*)d_in[4];
  const float* v_i    = (const float*)d_in[5];
  const float* pe_q_r = (const float*)d_in[6];
  const float* pe_q_i = (const float*)d_in[7];
  const float* pe_k_r = (const float*)d_in[8];
  const float* pe_k_i = (const float*)d_in[9];
  const float* wq_r = (const float*)d_in[10];
  const float* wq_i = (const float*)d_in[11];
  const float* bq_r = (const float*)d_in[12];
  const float* bq_i = (const float*)d_in[13];
  const float* wk_r = (const float*)d_in[14];
  const float* wk_i = (const float*)d_in[15];
  const float* bk_r = (const float*)d_in[16];
  const float* bk_i = (const float*)d_in[17];
  const float* wv_r = (const float*)d_in[18];
  const float* wv_i = (const float*)d_in[19];
  const float* bv_r = (const float*)d_in[20];
  const float* bv_i = (const float*)d_in[21];
  const float* wg_r = (const float*)d_in[22];
  const float* wg_i = (const float*)d_in[23];
  const float* bg_r = (const float*)d_in[24];
  const float* bg_i = (const float*)d_in[25];
  const float* wo_r = (const float*)d_in[26];
  const float* wo_i = (const float*)d_in[27];
  const float* bo_r = (const float*)d_in[28];
  const float* bo_i = (const float*)d_in[29];
  const float* lam_q1 = (const float*)d_in[30];
  const float* lam_k1 = (const float*)d_in[31];
  const float* lam_q2 = (const float*)d_in[32];
  const float* lam_k2 = (const float*)d_in[33];
  const float* subln_w = (const float*)d_in[34];

  char* base = (char*)d_ws;
  size_t off = 0;
  auto alloc = [&](size_t bytes) -> void* {
    void* p = base + off;
    off = (off + bytes + 255) & ~(size_t)255;
    return p;
  };
  f16*   Wq   = (f16*)alloc(2304L * 768 * 2);
  f16*   Wk   = (f16*)alloc(768L * 768 * 2);
  f16*   Wv   = (f16*)alloc(768L * 768 * 2);
  f16*   Wo   = (f16*)alloc(768L * 768 * 2);
  float* bq   = (float*)alloc(2304 * 4);
  float* bk   = (float*)alloc(768 * 4);
  float* bv   = (float*)alloc(768 * 4);
  float* bo   = (float*)alloc(768 * 4);
  float* lamp = (float*)alloc(4);
  f16*   X    = (f16*)alloc(NROW * 768 * 2);
  f16*   QG   = (f16*)alloc(NROW * 2304 * 2);   // [q1|q2|g] per row
  f16*   Kc   = (f16*)alloc(NROW * 768 * 2);
  f16*   Vt   = (f16*)alloc(16L * 768 * 1024 * 2);
  f16*   P    = (f16*)alloc(32L * 1024 * 1024 * 2);
  if (off > ws_size) return;
  // overlays onto dead regions:
  f16* A1   = Kc;   // dead after score
  f16* A2   = X;    // dead after V projection
  f16* Xatt = Vt;   // dead after pv

  // --- weight / scalar prep ---
  pack_wq<<<6912, 256, 0, stream>>>(wq_r, wq_i, wg_r, wg_i, bq_r, bq_i, bg_r, bg_i, Wq, bq);
  pack_w_std<<<2304, 256, 0, stream>>>(wk_r, wk_i, bk_r, bk_i, Wk, bk);
  pack_w_std<<<2304, 256, 0, stream>>>(wv_r, wv_i, bv_r, bv_i, Wv, bv);
  pack_w_std<<<2304, 256, 0, stream>>>(wo_r, wo_i, bo_r, bo_i, Wo, bo);
  lam_kernel<<<1, 128, 0, stream>>>(lam_q1, lam_k1, lam_q2, lam_k2, lamp);

  PeTab pe0{};

  // --- Q+G path (N=2304 -> gx=9, 576 blocks) ---
  pack_x<<<6144, 256, 0, stream>>>(q_r, q_i, X);
  PeTab peQ{};
  peQ.p[0] = pe_q_r; peQ.sgn[0] = 1.f;
  peQ.p[1] = pe_q_i; peQ.sgn[1] = 1.f;
  peQ.p[2] = pe_q_r; peQ.sgn[2] = 1.f;
  peQ.p[3] = pe_q_i; peQ.sgn[3] = 1.f;
  gemm256<MODE_PROJ><<<576, 512, 0, stream>>>(
      X, 768, Wq, 768, bq, peQ, QG, nullptr, 2304, 768, 9);

  // --- K path (gx=3, 192 blocks) ---
  pack_x<<<6144, 256, 0, stream>>>(k_r, k_i, X);
  PeTab peK{};
  peK.p[0] = pe_k_r; peK.sgn[0] = 1.f;
  peK.p[1] = pe_k_i; peK.sgn[1] = 1.f;
  gemm256<MODE_PROJ><<<192, 512, 0, stream>>>(
      X, 768, Wk, 768, bk, peK, Kc, nullptr, 768, 768, 3);

  // --- V path (transposed output Vt[bh][n][s]) ---
  pack_x<<<6144, 256, 0, stream>>>(v_r, v_i, X);
  gemm256<MODE_VT><<<192, 512, 0, stream>>>(
      X, 768, Wv, 768, bv, pe0, Vt, nullptr, 0, 768, 3);

  // --- attention ---
  score256<<<1024, 512, 0, stream>>>(QG, Kc, P);
  softmax_kernel<<<8192, 256, 0, stream>>>(P);
  gemm256<MODE_PV><<<384, 512, 0, stream>>>(
      P, 1024, Vt, 1024, nullptr, pe0, A1, A2, 0, 1024, 0);

  // --- norm + diff + gate ---
  fuse_kernel<<<16384, 128, 0, stream>>>(A1, A2, QG, subln_w, lamp, Xatt);

  // --- output projection ---
  gemm256<MODE_OUT><<<192, 512, 0, stream>>>(
      Xatt, 768, Wo, 768, bo, pe0, d_out, nullptr, 0, 768, 3);

  (void)in_sizes; (void)n_in; (void)out_size;
}

// Round 7
// 763.387 us; speedup vs baseline: 1.1194x; 1.1194x over previous
//
#include <hip/hip_runtime.h>
#include <cstdint>

// ---------------------------------------------------------------------------
// Complex differential attention block, MI355X (gfx950).
// B=2,H=8,S=1024,D=384.  Rows = B*H*S = 16384.
// fp16 MFMA (16x16x32), fp32 accumulate.
// R7: lesson from R2-R6: blocks/CU is the dominant lever (epilogue-heavy
//     GEMMs need cross-block overlap); 256²/128KB (1 blk/CU) is dead.
//     New shape: 128² tile, BK=64 dbuf = 64 KB LDS -> 2 blk/CU, counted
//     vmcnt(8), XOR swizzle (conflicts ~0).  score: 4-array structure
//     (64 MFMA/wave/epoch) + dbuf + counted, 64 KB -> 2 blk/CU.
//     PE tables prepacked to f16 (halves QG/K epilogue fetch), overlaid
//     on the not-yet-live P buffer.
// ---------------------------------------------------------------------------

typedef _Float16 f16;
typedef __attribute__((ext_vector_type(8))) _Float16 f16x8;
typedef __attribute__((ext_vector_type(4))) _Float16 f16x4;
typedef __attribute__((ext_vector_type(4))) float    f32x4;

#define NROW      16384L
#define HALF_OUT  6291456L               // NROW*384
#define SCALE_QK  0.05103103630798288f   // 384^-0.5
#define LAMBDA_INIT 0.35550906759096926f

__device__ __forceinline__ void gl2lds16(const void* g, void* l) {
  __builtin_amdgcn_global_load_lds(
      (const __attribute__((address_space(1))) void*)(uintptr_t)g,
      (__attribute__((address_space(3))) void*)(uint32_t)(uintptr_t)l,
      16, 0, 0);
}

enum { MODE_PROJ = 0, MODE_VT = 1, MODE_OUT = 2, MODE_PV = 3 };

// ---------------------------------------------------------------------------
// Unified C[M,N] = A[M,K] @ W[N,K]^T.  256 thr (4 waves, 2Mx2N), tile
// 128x128, BK=64 epochs, 2 LDS buffers (64 KB -> 2 blk/CU).  Counted
// depth-2 pipeline: 8 gl2lds/thread/epoch, vmcnt(8) keeps next epoch's
// loads in flight; raw s_barrier (no implicit drain).
// LDS rows = 8 chunks of 16B; swizzle: LDS (r,c) holds global (r, c^(r&7))
// via pre-swizzled global source + swizzled ds_read (linear gl2lds dest).
// Modes: PROJ (f16 out + bias + f16 pe), VT (Vt[bh][n][s]), OUT (fp32
// planar), PV (A = stacked P1/P2 rows per bh, out O1/O2).
// Grids (1D, XCD-major), xcd=bid&7, per=bid>>3:
//  PROJ/VT/OUT: grid = 8*16*gx; row_t = xcd*16+per/gx, col_t = per%gx.
//  PV: grid 1536; bh = xcd*2+per/96, rem=per%96, row0s=(rem/6)*128 (stacked
//      0..2047, uniform halves), col0=(rem%6)*128.
// ---------------------------------------------------------------------------
template <int MODE>
__launch_bounds__(256, 2)
__global__ void gemm128(const f16* __restrict__ A, int lda,
                        const f16* __restrict__ W, int ldw,
                        const float* __restrict__ bias,
                        const f16* __restrict__ pe16, int pelim,
                        void* __restrict__ outp, void* __restrict__ outp2,
                        int ldo, int K, int gx)
{
  __shared__ f16 As[2][128 * 64];
  __shared__ f16 Bs[2][128 * 64];
  const int t    = threadIdx.x;
  const int lane = t & 63;
  const int wave = t >> 6;
  const int bid  = blockIdx.x;
  const int xcd  = bid & 7;
  const int per  = bid >> 3;

  long row0, col0;
  const f16 *Ab, *Wb;
  int bh = 0;
  if (MODE == MODE_PV) {
    bh = xcd * 2 + per / 96;
    const int rem = per % 96;
    row0 = (long)(rem / 6) * 128;             // stacked row in [0,2048)
    col0 = (long)(rem % 6) * 128;
    const int slab = bh + (row0 >= 1024 ? 16 : 0);
    Ab = A + ((long)slab << 20) + (row0 & 1023) * (long)lda;
    Wb = W + (long)bh * 768 * 1024 + col0 * (long)ldw;
  } else {
    row0 = (long)(xcd * 16 + per / gx) * 128;
    col0 = (long)(per % gx) * 128;
    Ab = A + row0 * (long)lda;
    Wb = W + col0 * (long)ldw;
  }

  const int wm = (wave >> 1) * 64;
  const int wn = (wave & 1) * 64;
  const int lm = lane & 15;
  const int l4 = lane >> 4;

  f32x4 acc[4][4] = {};

  // one BK=64 tile pair: 128 rows x 8 chunks = 1024 slots/array,
  // 4 slots/thread/array -> 8 gl2lds/thread.
  auto stage = [&](int kk, int sub) {
#pragma unroll
    for (int p = 0; p < 4; ++p) {
      int sg = p * 256 + t;
      int r = sg >> 3, cl = sg & 7, cg = cl ^ (r & 7);
      gl2lds16(Ab + (long)r * lda + kk + cg * 8, &As[sub][sg * 8]);
      gl2lds16(Wb + (long)r * ldw + kk + cg * 8, &Bs[sub][sg * 8]);
    }
  };

  const int NT = K >> 6;
  stage(0, 0);
  stage(64, 1);
  int cur = 0;
  for (int it = 0; it < NT; ++it) {
    if (it + 1 < NT) asm volatile("s_waitcnt vmcnt(8)" ::: "memory");
    else             asm volatile("s_waitcnt vmcnt(0)" ::: "memory");
    __builtin_amdgcn_s_barrier();             // stage(it) visible everywhere
#pragma unroll
    for (int ks = 0; ks < 2; ++ks) {
      f16x8 bfr[4];
#pragma unroll
      for (int nt = 0; nt < 4; ++nt) {
        int rr = wn + nt * 16 + lm;
        bfr[nt] = *(const f16x8*)&Bs[cur][rr * 64 + (((ks * 4 + l4) ^ (rr & 7)) << 3)];
      }
#pragma unroll
      for (int mt = 0; mt < 4; ++mt) {
        int rr = wm + mt * 16 + lm;
        f16x8 afr = *(const f16x8*)&As[cur][rr * 64 + (((ks * 4 + l4) ^ (rr & 7)) << 3)];
#pragma unroll
        for (int nt = 0; nt < 4; ++nt)
          acc[mt][nt] = __builtin_amdgcn_mfma_f32_16x16x32_f16(afr, bfr[nt], acc[mt][nt], 0, 0, 0);
      }
    }
    __builtin_amdgcn_s_barrier();             // all reads of buf[cur] done
    if (it + 2 < NT) stage((it + 2) << 6, cur);
    cur ^= 1;
  }

  const int lm4 = l4 * 4;
  const int ln  = lm;
#pragma unroll
  for (int mt = 0; mt < 4; ++mt) {
#pragma unroll
    for (int nt = 0; nt < 4; ++nt) {
      int col = (int)col0 + wn + nt * 16 + ln;
      if (MODE == MODE_VT) {
        long rowb = row0 + wm + mt * 16 + lm4;
        long vbh = rowb >> 10, sx = rowb & 1023;
        f16x4 v;
#pragma unroll
        for (int r = 0; r < 4; ++r) v[r] = (f16)(acc[mt][nt][r] + bias[col]);
        *(f16x4*)&((f16*)outp)[(vbh * 768 + col) * 1024 + sx] = v;   // Vt[bh][n][s]
      } else if (MODE == MODE_PV) {
#pragma unroll
        for (int r = 0; r < 4; ++r) {
          long grow = row0 + wm + mt * 16 + lm4 + r;   // 0..2047, uniform half
          f16 val = (f16)acc[mt][nt][r];
          if (grow < 1024) ((f16*)outp )[((long)bh * 1024 + grow)        * 768 + col] = val;
          else             ((f16*)outp2)[((long)bh * 1024 + grow - 1024) * 768 + col] = val;
        }
      } else {
#pragma unroll
        for (int r = 0; r < 4; ++r) {
          long row = row0 + wm + mt * 16 + lm4 + r;
          float c = acc[mt][nt][r] + bias[col];
          if (MODE == MODE_PROJ) {
            if (col < pelim) {
              int pc = col < 768 ? col : col - 768;
              c += (float)pe16[row * 768 + pc];
            }
            ((f16*)outp)[row * (long)ldo + col] = (f16)c;
          } else {  // MODE_OUT
            float* of = (float*)outp;
            if (col < 384) of[row * 384 + col] = c;
            else           of[HALF_OUT + row * 384 + (col - 384)] = c;
          }
        }
      }
    }
  }
}

// ---------------------------------------------------------------------------
// Score for slab (w,bh): A = QG[bh] cols [w*768..+767] = [q_r|q_i],
// B = Kc[bh] = [k_r|k_i].  s_r = qr.kr + qi.ki ; s_i = qi.kr - qr.ki.
// 4 stage arrays (AsL/AsH/BsL/BsH), BK=32, double-buffered (64 KB ->
// 2 blk/CU), counted vmcnt(8), XOR-4 swizzle (16B chunks, cg = cl^(r&3)).
// 64 MFMA/wave/epoch, 12 epochs.  |s|*scale -> fp16 logits.
// Grid 2048: xcd=bid&7, per=bid>>3; z=xcd*4+per/64 (=w*16+bh); rem=per%64:
// row0=(rem/8)*128, col0=(rem%8)*128.
// ---------------------------------------------------------------------------
__launch_bounds__(256, 2)
__global__ void score128(const f16* __restrict__ QG, const f16* __restrict__ Kc,
                         f16* __restrict__ P)
{
  __shared__ f16 AsL[2][128 * 32], AsH[2][128 * 32];
  __shared__ f16 BsL[2][128 * 32], BsH[2][128 * 32];
  const int t = threadIdx.x, lane = t & 63, wave = t >> 6;
  const int bid = blockIdx.x;
  const int xcd = bid & 7, per = bid >> 3;
  const int z   = xcd * 4 + per / 64;
  const int rem = per % 64;
  const int w = z >> 4, bh = z & 15;
  const long row0 = (long)(rem / 8) * 128, col0 = (long)(rem % 8) * 128;
  const f16* A = QG + (long)bh * 1024 * 2304 + row0 * 2304 + w * 768;
  const f16* B = Kc + (long)bh * 1024 * 768 + col0 * 768;
  f16* Pz = P + ((long)z << 20);

  const int wm = (wave >> 1) * 64, wn = (wave & 1) * 64;
  const int lm = lane & 15, l4 = lane >> 4;
  f32x4 accr[4][4] = {}, acci[4][4] = {};

  // 128 rows x 4 chunks = 512 slots/array, 2 slots/thread/array ->
  // 8 gl2lds/thread/epoch.
  auto stage = [&](int kk, int sub) {
#pragma unroll
    for (int p = 0; p < 2; ++p) {
      int sg = p * 256 + t;
      int r = sg >> 2, cl = sg & 3, cg = cl ^ (r & 3);
      gl2lds16(A + (long)r * 2304 + kk + cg * 8,       &AsL[sub][sg * 8]);
      gl2lds16(A + (long)r * 2304 + 384 + kk + cg * 8, &AsH[sub][sg * 8]);
      gl2lds16(B + (long)r * 768 + kk + cg * 8,        &BsL[sub][sg * 8]);
      gl2lds16(B + (long)r * 768 + 384 + kk + cg * 8,  &BsH[sub][sg * 8]);
    }
  };

  stage(0, 0);
  stage(32, 1);
  int cur = 0;
  for (int it = 0; it < 12; ++it) {
    if (it + 1 < 12) asm volatile("s_waitcnt vmcnt(8)" ::: "memory");
    else             asm volatile("s_waitcnt vmcnt(0)" ::: "memory");
    __builtin_amdgcn_s_barrier();
    f16x8 bl[4], bh2[4];
#pragma unroll
    for (int nt = 0; nt < 4; ++nt) {
      int rr = wn + nt * 16 + lm;
      int off = rr * 32 + (((l4 ^ (rr & 3))) << 3);
      bl[nt]  = *(const f16x8*)&BsL[cur][off];
      bh2[nt] = *(const f16x8*)&BsH[cur][off];
    }
#pragma unroll
    for (int mt = 0; mt < 4; ++mt) {
      int rr = wm + mt * 16 + lm;
      int off = rr * 32 + (((l4 ^ (rr & 3))) << 3);
      f16x8 al  = *(const f16x8*)&AsL[cur][off];
      f16x8 ah  = *(const f16x8*)&AsH[cur][off];
      f16x8 nal = -al;
#pragma unroll
      for (int nt = 0; nt < 4; ++nt) {
        accr[mt][nt] = __builtin_amdgcn_mfma_f32_16x16x32_f16(al,  bl[nt],  accr[mt][nt], 0, 0, 0);
        accr[mt][nt] = __builtin_amdgcn_mfma_f32_16x16x32_f16(ah,  bh2[nt], accr[mt][nt], 0, 0, 0);
        acci[mt][nt] = __builtin_amdgcn_mfma_f32_16x16x32_f16(ah,  bl[nt],  acci[mt][nt], 0, 0, 0);
        acci[mt][nt] = __builtin_amdgcn_mfma_f32_16x16x32_f16(nal, bh2[nt], acci[mt][nt], 0, 0, 0);
      }
    }
    __builtin_amdgcn_s_barrier();
    if (it + 2 < 12) stage((it + 2) << 5, cur);
    cur ^= 1;
  }
  const int lm4 = l4 * 4, ln = lm;
#pragma unroll
  for (int mt = 0; mt < 4; ++mt)
#pragma unroll
    for (int nt = 0; nt < 4; ++nt) {
      int col = (int)col0 + wn + nt * 16 + ln;
#pragma unroll
      for (int r = 0; r < 4; ++r) {
        long row = row0 + wm + mt * 16 + lm4 + r;
        float sr = accr[mt][nt][r], si = acci[mt][nt][r];
        float m = sqrtf(sr * sr + si * si + 1e-8f) * SCALE_QK;
        Pz[row * 1024 + col] = (f16)m;
      }
    }
}

// In-place row softmax over 1024 logits; 1 wave per row, 4 rows per block.
__global__ void softmax_kernel(f16* __restrict__ P)
{
  const long row = (long)blockIdx.x * 4 + (threadIdx.x >> 6);
  f16* p = P + row * 1024;
  const int lane = threadIdx.x & 63;
  f16x8 v0 = *(const f16x8*)(p + lane * 16);
  f16x8 v1 = *(const f16x8*)(p + lane * 16 + 8);
  float x[16];
#pragma unroll
  for (int i = 0; i < 8; ++i) { x[i] = (float)v0[i]; x[8 + i] = (float)v1[i]; }
  float m = x[0];
#pragma unroll
  for (int i = 1; i < 16; ++i) m = fmaxf(m, x[i]);
#pragma unroll
  for (int off = 1; off < 64; off <<= 1) m = fmaxf(m, __shfl_xor(m, off));
  float s = 0.f;
#pragma unroll
  for (int i = 0; i < 16; ++i) { x[i] = __expf(x[i] - m); s += x[i]; }
#pragma unroll
  for (int off = 1; off < 64; off <<= 1) s += __shfl_xor(s, off);
  float inv = 1.f / s;
  f16x8 o0, o1;
#pragma unroll
  for (int i = 0; i < 8; ++i) { o0[i] = (f16)(x[i] * inv); o1[i] = (f16)(x[8 + i] * inv); }
  *(f16x8*)(p + lane * 16)     = o0;
  *(f16x8*)(p + lane * 16 + 8) = o1;
}

// RMSNorm over cat(a1,a2) + lambda diff + complex gate -> Xatt fp16.
// G lives in QG cols 1536..2303.
__global__ void fuse_kernel(const f16* __restrict__ A1, const f16* __restrict__ A2,
                            const f16* __restrict__ QG, const float* __restrict__ subw,
                            const float* __restrict__ lamp, f16* __restrict__ Xatt)
{
  const long row = blockIdx.x;
  const int t = threadIdx.x, lane = t & 63, wv = t >> 6;
  const f16* a1 = A1 + row * 768;
  const f16* a2 = A2 + row * 768;
  const f16* g  = QG + row * 2304 + 1536;
  float a1r[3], a1i[3], a2r[3], a2i[3];
  float ss = 0.f;
#pragma unroll
  for (int q = 0; q < 3; ++q) {
    int d = t + q * 128;
    a1r[q] = (float)a1[d]; a1i[q] = (float)a1[d + 384];
    a2r[q] = (float)a2[d]; a2i[q] = (float)a2[d + 384];
    ss += a1r[q] * a1r[q] + a1i[q] * a1i[q] + a2r[q] * a2r[q] + a2i[q] * a2i[q];
  }
#pragma unroll
  for (int m = 1; m < 64; m <<= 1) ss += __shfl_xor(ss, m);
  __shared__ float part[2];
  if (lane == 0) part[wv] = ss;
  __syncthreads();
  float inv = rsqrtf((part[0] + part[1]) * (1.f / 768.f) + 1e-5f);
  float lam = lamp[0];
#pragma unroll
  for (int q = 0; q < 3; ++q) {
    int d = t + q * 128;
    float w1 = subw[d], w2 = subw[d + 384];
    float n1r = a1r[q] * inv * w1, n1i = a1i[q] * inv * w1;
    float n2r = a2r[q] * inv * w2, n2i = a2i[q] * inv * w2;
    float orr = n1r - lam * n2r, oii = n1i - lam * n2i;
    float gr = (float)g[d], gi = (float)g[d + 384];
    Xatt[row * 768 + d]       = (f16)(gr * orr - gi * oii);
    Xatt[row * 768 + d + 384] = (f16)(gr * oii + gi * orr);
  }
}

__global__ void lam_kernel(const float* lq1, const float* lk1,
                           const float* lq2, const float* lk2, float* out)
{
  const int t = threadIdx.x, lane = t & 63, wv = t >> 6;
  float s1 = 0.f, s2 = 0.f;
#pragma unroll
  for (int q = 0; q < 3; ++q) {
    int d = t + q * 128;
    s1 += lq1[d] * lk1[d];
    s2 += lq2[d] * lk2[d];
  }
#pragma unroll
  for (int m = 1; m < 64; m <<= 1) { s1 += __shfl_xor(s1, m); s2 += __shfl_xor(s2, m); }
  __shared__ float p1[2], p2[2];
  if (lane == 0) { p1[wv] = s1; p2[wv] = s2; }
  __syncthreads();
  if (t == 0) {
    float x = expf(p1[0] + p1[1]) - expf(p2[0] + p2[1]) + LAMBDA_INIT;
    out[0] = 1.f / (1.f + expf(-x));
  }
}

// X = [xr | xi] fp16, row-major [16384][768].  8 elements per thread.
// Also used to pack PE tables to f16.
__global__ void pack_x(const float* __restrict__ xr, const float* __restrict__ xi,
                       f16* __restrict__ X)
{
  long i = (long)blockIdx.x * 256 + threadIdx.x;   // < 16384*96
  long row = i / 96;
  int  rem = (int)(i - row * 96);
  int  c   = rem * 8;
  const float* src = (c < 384) ? (xr + row * 384 + c) : (xi + row * 384 + (c - 384));
  f16x8 o;
#pragma unroll
  for (int j = 0; j < 8; ++j) o[j] = (f16)src[j];
  *(f16x8*)&X[row * 768 + c] = o;
}

// Wq' [2304][768]: sections of 384 rows: 0:q1_r 1:q1_i 2:q2_r 3:q2_i 4:g_r 5:g_i
__global__ void pack_wq(const float* wq_r, const float* wq_i,
                        const float* wg_r, const float* wg_i,
                        const float* bq_r, const float* bq_i,
                        const float* bg_r, const float* bg_i,
                        f16* __restrict__ Wp, float* __restrict__ bp)
{
  long i = (long)blockIdx.x * 256 + threadIdx.x;   // < 2304*768
  int n = (int)(i / 768), e = (int)(i % 768);
  int s = n / 384, d = n - s * 384;
  int hb = (e >= 384);
  int ee = e - hb * 384;
  float v = 0.f, b = 0.f;
  switch (s) {
    case 0: v = hb ? -wq_i[d * 384 + ee]         :  wq_r[d * 384 + ee];         b = bq_r[d];       break;
    case 1: v = hb ?  wq_r[d * 384 + ee]         :  wq_i[d * 384 + ee];         b = bq_i[d];       break;
    case 2: v = hb ? -wq_i[(384 + d) * 384 + ee] :  wq_r[(384 + d) * 384 + ee]; b = bq_r[384 + d]; break;
    case 3: v = hb ?  wq_r[(384 + d) * 384 + ee] :  wq_i[(384 + d) * 384 + ee]; b = bq_i[384 + d]; break;
    case 4: v = hb ? -wg_i[d * 384 + ee]         :  wg_r[d * 384 + ee];         b = bg_r[d];       break;
    case 5: v = hb ?  wg_r[d * 384 + ee]         :  wg_i[d * 384 + ee];         b = bg_i[d];       break;
  }
  Wp[i] = (f16)v;
  if (e == 0) bp[n] = b;
}

// standard complex-linear pack: rows [o_r(384) | o_i(384)]
__global__ void pack_w_std(const float* wr, const float* wi,
                           const float* br, const float* bi,
                           f16* __restrict__ Wp, float* __restrict__ bp)
{
  long i = (long)blockIdx.x * 256 + threadIdx.x;   // < 768*768
  int n = (int)(i / 768), e = (int)(i % 768);
  int hb = (e >= 384);
  int ee = e - hb * 384;
  float v, b;
  if (n < 384) { v = hb ? -wi[n * 384 + ee] : wr[n * 384 + ee]; b = br[n]; }
  else { int d = n - 384; v = hb ? wr[d * 384 + ee] : wi[d * 384 + ee]; b = bi[d]; }
  Wp[i] = (f16)v;
  if (e == 0) bp[n] = b;
}

// ---------------------------------------------------------------------------
extern "C" void kernel_launch(void* const* d_in, const int* in_sizes, int n_in,
                              void* d_out, int out_size, void* d_ws, size_t ws_size,
                              hipStream_t stream)
{
  const float* q_r    = (const float*)d_in[0];
  const float* q_i    = (const float*)d_in[1];
  const float* k_r    = (const float*)d_in[2];
  const float* k_i    = (const float*)d_in[3];
  const float* v_r    = (const float*)d_in[4];
  const float* v_i    = (const float*)d_in[5];
  const float* pe_q_r = (const float*)d_in[6];
  const float* pe_q_i = (const float*)d_in[7];
  const float* pe_k_r = (const float*)d_in[8];
  const float* pe_k_i = (const float*)d_in[9];
  const float* wq_r = (const float*)d_in[10];
  const float* wq_i = (const float*)d_in[11];
  const float* bq_r = (const float*)d_in[12];
  const float* bq_i = (const float*)d_in[13];
  const float* wk_r = (const float*)d_in[14];
  const float* wk_i = (const float*)d_in[15];
  const float* bk_r = (const float*)d_in[16];
  const float* bk_i = (const float*)d_in[17];
  const float* wv_r = (const float*)d_in[18];
  const float* wv_i = (const float*)d_in[19];
  const float* bv_r = (const float*)d_in[20];
  const float* bv_i = (const float*)d_in[21];
  const float* wg_r = (const float*)d_in[22];
  const float* wg_i = (const float*)d_in[23];
  const float* bg_r = (const float*)d_in[24];
  const float* bg_i = (const float*)d_in[25];
  const float* wo_r = (const float*)d_in[26];
  const float* wo_i = (const float*)d_in[27];
  const float* bo_r = (const float*)d_in[28];
  const float* bo_i = (const float*)d_in[29];
  const float* lam_q1 = (const float*)d_in[30];
  const float* lam_k1 = (const float*)d_in[31];
  const float* lam_q2 = (const float*)d_in[32];
  const float* lam_k2 = (const float*)d_in[33];
  const float* subln_w = (const float*)d_in[34];

  char* base = (char*)d_ws;
  size_t off = 0;
  auto alloc = [&](size_t bytes) -> void* {
    void* p = base + off;
    off = (off + bytes + 255) & ~(size_t)255;
    return p;
  };
  f16*   Wq   = (f16*)alloc(2304L * 768 * 2);
  f16*   Wk   = (f16*)alloc(768L * 768 * 2);
  f16*   Wv   = (f16*)alloc(768L * 768 * 2);
  f16*   Wo   = (f16*)alloc(768L * 768 * 2);
  float* bq   = (float*)alloc(2304 * 4);
  float* bk   = (float*)alloc(768 * 4);
  float* bv   = (float*)alloc(768 * 4);
  float* bo   = (float*)alloc(768 * 4);
  float* lamp = (float*)alloc(4);
  f16*   X    = (f16*)alloc(NROW * 768 * 2);
  f16*   QG   = (f16*)alloc(NROW * 2304 * 2);   // [q1|q2|g] per row
  f16*   Kc   = (f16*)alloc(NROW * 768 * 2);
  f16*   Vt   = (f16*)alloc(16L * 768 * 1024 * 2);
  f16*   P    = (f16*)alloc(32L * 1024 * 1024 * 2);
  if (off > ws_size) return;
  // overlays onto dead regions:
  f16* A1   = Kc;                  // dead after score
  f16* A2   = X;                   // dead after V projection
  f16* Xatt = Vt;                  // dead after pv
  f16* PEQ  = P;                   // P not live until score
  f16* PEK  = P + NROW * 768;

  // --- weight / scalar / PE prep ---
  pack_wq<<<6912, 256, 0, stream>>>(wq_r, wq_i, wg_r, wg_i, bq_r, bq_i, bg_r, bg_i, Wq, bq);
  pack_w_std<<<2304, 256, 0, stream>>>(wk_r, wk_i, bk_r, bk_i, Wk, bk);
  pack_w_std<<<2304, 256, 0, stream>>>(wv_r, wv_i, bv_r, bv_i, Wv, bv);
  pack_w_std<<<2304, 256, 0, stream>>>(wo_r, wo_i, bo_r, bo_i, Wo, bo);
  lam_kernel<<<1, 128, 0, stream>>>(lam_q1, lam_k1, lam_q2, lam_k2, lamp);
  pack_x<<<6144, 256, 0, stream>>>(pe_q_r, pe_q_i, PEQ);
  pack_x<<<6144, 256, 0, stream>>>(pe_k_r, pe_k_i, PEK);

  // --- Q+G path (N=2304 -> gx=18, grid 2304) ---
  pack_x<<<6144, 256, 0, stream>>>(q_r, q_i, X);
  gemm128<MODE_PROJ><<<2304, 256, 0, stream>>>(
      X, 768, Wq, 768, bq, PEQ, 1536, QG, nullptr, 2304, 768, 18);

  // --- K path (gx=6, grid 768) ---
  pack_x<<<6144, 256, 0, stream>>>(k_r, k_i, X);
  gemm128<MODE_PROJ><<<768, 256, 0, stream>>>(
      X, 768, Wk, 768, bk, PEK, 768, Kc, nullptr, 768, 768, 6);

  // --- V path (transposed output Vt[bh][n][s]) ---
  pack_x<<<6144, 256, 0, stream>>>(v_r, v_i, X);
  gemm128<MODE_VT><<<768, 256, 0, stream>>>(
      X, 768, Wv, 768, bv, nullptr, 0, Vt, nullptr, 0, 768, 6);

  // --- attention ---
  score128<<<2048, 256, 0, stream>>>(QG, Kc, P);
  softmax_kernel<<<8192, 256, 0, stream>>>(P);
  gemm128<MODE_PV><<<1536, 256, 0, stream>>>(
      P, 1024, Vt, 1024, nullptr, nullptr, 0, A1, A2, 0, 1024, 0);

  // --- norm + diff + gate ---
  fuse_kernel<<<16384, 128, 0, stream>>>(A1, A2, QG, subln_w, lamp, Xatt);

  // --- output projection ---
  gemm128<MODE_OUT><<<768, 256, 0, stream>>>(
      Xatt, 768, Wo, 768, bo, nullptr, 0, d_out, nullptr, 0, 768, 6);

  (void)in_sizes; (void)n_in; (void)out_size;
}

// Round 8
// 748.215 us; speedup vs baseline: 1.1421x; 1.0203x over previous
//
#include <hip/hip_runtime.h>
#include <cstdint>

// ---------------------------------------------------------------------------
// Complex differential attention block, MI355X (gfx950).
// B=2,H=8,S=1024,D=384.  Rows = B*H*S = 16384.
// fp16 MFMA (16x16x32), fp32 accumulate.
// R8 (from R7's 763us):
//  1) score: merge L/H stage arrays into [128][64] (128B rows, XOR-8
//     chunk swizzle) -> conflict-free ds_read_b128 (R7 had 6.3M conflicts
//     from 64B rows / XOR-4).  Same 64KB LDS, 2 blk/CU, counted vmcnt(8).
//  2) launch-count 18 -> 7: one range-dispatched prep kernel (4 weight
//     packs + 5 x/PE packs + lam), one proj_all kernel (QG+K+V share the
//     proven gemm128 K-loop, runtime range dispatch).  Xk/Xv scratch lives
//     in d_out (dead until final GEMM overwrites it).
// ---------------------------------------------------------------------------

typedef _Float16 f16;
typedef __attribute__((ext_vector_type(8))) _Float16 f16x8;
typedef __attribute__((ext_vector_type(4))) _Float16 f16x4;
typedef __attribute__((ext_vector_type(4))) float    f32x4;

#define NROW      16384L
#define HALF_OUT  6291456L               // NROW*384
#define SCALE_QK  0.05103103630798288f   // 384^-0.5
#define LAMBDA_INIT 0.35550906759096926f

__device__ __forceinline__ void gl2lds16(const void* g, void* l) {
  __builtin_amdgcn_global_load_lds(
      (const __attribute__((address_space(1))) void*)(uintptr_t)g,
      (__attribute__((address_space(3))) void*)(uint32_t)(uintptr_t)l,
      16, 0, 0);
}

enum { MODE_PROJ = 0, MODE_VT = 1, MODE_OUT = 2, MODE_PV = 3 };

// ---------------------------------------------------------------------------
// gemm128 (PV / OUT modes): C[M,N] = A[M,K] @ W[N,K]^T.  256 thr (4 waves,
// 2Mx2N), tile 128x128, BK=64 epochs, 2 LDS buffers (64 KB -> 2 blk/CU).
// Counted depth-2 pipeline: 8 gl2lds/thread/epoch, vmcnt(8); raw s_barrier.
// LDS rows = 8 chunks of 16B (128B rows); swizzle cg = cl^(r&7), conflict-
// free.  PV: A = stacked P1/P2 rows per bh -> O1/O2.  OUT: fp32 planar.
// ---------------------------------------------------------------------------
template <int MODE>
__launch_bounds__(256, 2)
__global__ void gemm128(const f16* __restrict__ A, int lda,
                        const f16* __restrict__ W, int ldw,
                        const float* __restrict__ bias,
                        const f16* __restrict__ pe16, int pelim,
                        void* __restrict__ outp, void* __restrict__ outp2,
                        int ldo, int K, int gx)
{
  __shared__ f16 As[2][128 * 64];
  __shared__ f16 Bs[2][128 * 64];
  const int t    = threadIdx.x;
  const int lane = t & 63;
  const int wave = t >> 6;
  const int bid  = blockIdx.x;
  const int xcd  = bid & 7;
  const int per  = bid >> 3;

  long row0, col0;
  const f16 *Ab, *Wb;
  int bh = 0;
  if (MODE == MODE_PV) {
    bh = xcd * 2 + per / 96;
    const int rem = per % 96;
    row0 = (long)(rem / 6) * 128;             // stacked row in [0,2048)
    col0 = (long)(rem % 6) * 128;
    const int slab = bh + (row0 >= 1024 ? 16 : 0);
    Ab = A + ((long)slab << 20) + (row0 & 1023) * (long)lda;
    Wb = W + (long)bh * 768 * 1024 + col0 * (long)ldw;
  } else {
    row0 = (long)(xcd * 16 + per / gx) * 128;
    col0 = (long)(per % gx) * 128;
    Ab = A + row0 * (long)lda;
    Wb = W + col0 * (long)ldw;
  }

  const int wm = (wave >> 1) * 64;
  const int wn = (wave & 1) * 64;
  const int lm = lane & 15;
  const int l4 = lane >> 4;

  f32x4 acc[4][4] = {};

  auto stage = [&](int kk, int sub) {
#pragma unroll
    for (int p = 0; p < 4; ++p) {
      int sg = p * 256 + t;
      int r = sg >> 3, cl = sg & 7, cg = cl ^ (r & 7);
      gl2lds16(Ab + (long)r * lda + kk + cg * 8, &As[sub][sg * 8]);
      gl2lds16(Wb + (long)r * ldw + kk + cg * 8, &Bs[sub][sg * 8]);
    }
  };

  const int NT = K >> 6;
  stage(0, 0);
  stage(64, 1);
  int cur = 0;
  for (int it = 0; it < NT; ++it) {
    if (it + 1 < NT) asm volatile("s_waitcnt vmcnt(8)" ::: "memory");
    else             asm volatile("s_waitcnt vmcnt(0)" ::: "memory");
    __builtin_amdgcn_s_barrier();
#pragma unroll
    for (int ks = 0; ks < 2; ++ks) {
      f16x8 bfr[4];
#pragma unroll
      for (int nt = 0; nt < 4; ++nt) {
        int rr = wn + nt * 16 + lm;
        bfr[nt] = *(const f16x8*)&Bs[cur][rr * 64 + (((ks * 4 + l4) ^ (rr & 7)) << 3)];
      }
#pragma unroll
      for (int mt = 0; mt < 4; ++mt) {
        int rr = wm + mt * 16 + lm;
        f16x8 afr = *(const f16x8*)&As[cur][rr * 64 + (((ks * 4 + l4) ^ (rr & 7)) << 3)];
#pragma unroll
        for (int nt = 0; nt < 4; ++nt)
          acc[mt][nt] = __builtin_amdgcn_mfma_f32_16x16x32_f16(afr, bfr[nt], acc[mt][nt], 0, 0, 0);
      }
    }
    __builtin_amdgcn_s_barrier();
    if (it + 2 < NT) stage((it + 2) << 6, cur);
    cur ^= 1;
  }

  const int lm4 = l4 * 4;
  const int ln  = lm;
#pragma unroll
  for (int mt = 0; mt < 4; ++mt) {
#pragma unroll
    for (int nt = 0; nt < 4; ++nt) {
      int col = (int)col0 + wn + nt * 16 + ln;
      if (MODE == MODE_PV) {
#pragma unroll
        for (int r = 0; r < 4; ++r) {
          long grow = row0 + wm + mt * 16 + lm4 + r;   // 0..2047, uniform half
          f16 val = (f16)acc[mt][nt][r];
          if (grow < 1024) ((f16*)outp )[((long)bh * 1024 + grow)        * 768 + col] = val;
          else             ((f16*)outp2)[((long)bh * 1024 + grow - 1024) * 768 + col] = val;
        }
      } else {  // MODE_OUT
#pragma unroll
        for (int r = 0; r < 4; ++r) {
          long row = row0 + wm + mt * 16 + lm4 + r;
          float c = acc[mt][nt][r] + bias[col];
          float* of = (float*)outp;
          if (col < 384) of[row * 384 + col] = c;
          else           of[HALF_OUT + row * 384 + (col - 384)] = c;
        }
      }
    }
  }
}

// ---------------------------------------------------------------------------
// proj_all: QG (2304 blocks, gx=18), K (768, gx=6), V->Vt (768, gx=6) in one
// launch.  Same K-loop as gemm128 (K=768, lda=ldw=768, NT=12).
// ---------------------------------------------------------------------------
__launch_bounds__(256, 2)
__global__ void proj_all(const f16* __restrict__ Xq, const f16* __restrict__ Xk,
                         const f16* __restrict__ Xv,
                         const f16* __restrict__ Wq, const f16* __restrict__ Wk,
                         const f16* __restrict__ Wv,
                         const float* __restrict__ bq, const float* __restrict__ bk,
                         const float* __restrict__ bv,
                         const f16* __restrict__ PEQ, const f16* __restrict__ PEK,
                         f16* __restrict__ QG, f16* __restrict__ Kc,
                         f16* __restrict__ Vt)
{
  __shared__ f16 As[2][128 * 64];
  __shared__ f16 Bs[2][128 * 64];
  const int t = threadIdx.x, lane = t & 63, wave = t >> 6;
  const int bid = blockIdx.x;

  const f16 *A, *W; const float* bias; const f16* pe;
  int pelim, gx, ldo, lb; f16* outp; bool vt = false;
  if (bid < 2304)      { A = Xq; W = Wq; bias = bq; pe = PEQ; pelim = 1536; gx = 18; outp = QG; ldo = 2304; lb = bid; }
  else if (bid < 3072) { A = Xk; W = Wk; bias = bk; pe = PEK; pelim = 768;  gx = 6;  outp = Kc; ldo = 768;  lb = bid - 2304; }
  else                 { A = Xv; W = Wv; bias = bv; pe = nullptr; pelim = 0; gx = 6; outp = Vt; ldo = 0;    lb = bid - 3072; vt = true; }

  const int xcd = lb & 7, per = lb >> 3;
  const long row0 = (long)(xcd * 16 + per / gx) * 128;
  const long col0 = (long)(per % gx) * 128;
  const f16* Ab = A + row0 * 768;
  const f16* Wb = W + col0 * 768;

  const int wm = (wave >> 1) * 64, wn = (wave & 1) * 64;
  const int lm = lane & 15, l4 = lane >> 4;
  f32x4 acc[4][4] = {};

  auto stage = [&](int kk, int sub) {
#pragma unroll
    for (int p = 0; p < 4; ++p) {
      int sg = p * 256 + t;
      int r = sg >> 3, cl = sg & 7, cg = cl ^ (r & 7);
      gl2lds16(Ab + (long)r * 768 + kk + cg * 8, &As[sub][sg * 8]);
      gl2lds16(Wb + (long)r * 768 + kk + cg * 8, &Bs[sub][sg * 8]);
    }
  };

  stage(0, 0);
  stage(64, 1);
  int cur = 0;
  for (int it = 0; it < 12; ++it) {
    if (it + 1 < 12) asm volatile("s_waitcnt vmcnt(8)" ::: "memory");
    else             asm volatile("s_waitcnt vmcnt(0)" ::: "memory");
    __builtin_amdgcn_s_barrier();
#pragma unroll
    for (int ks = 0; ks < 2; ++ks) {
      f16x8 bfr[4];
#pragma unroll
      for (int nt = 0; nt < 4; ++nt) {
        int rr = wn + nt * 16 + lm;
        bfr[nt] = *(const f16x8*)&Bs[cur][rr * 64 + (((ks * 4 + l4) ^ (rr & 7)) << 3)];
      }
#pragma unroll
      for (int mt = 0; mt < 4; ++mt) {
        int rr = wm + mt * 16 + lm;
        f16x8 afr = *(const f16x8*)&As[cur][rr * 64 + (((ks * 4 + l4) ^ (rr & 7)) << 3)];
#pragma unroll
        for (int nt = 0; nt < 4; ++nt)
          acc[mt][nt] = __builtin_amdgcn_mfma_f32_16x16x32_f16(afr, bfr[nt], acc[mt][nt], 0, 0, 0);
      }
    }
    __builtin_amdgcn_s_barrier();
    if (it + 2 < 12) stage((it + 2) << 6, cur);
    cur ^= 1;
  }

  const int lm4 = l4 * 4, ln = lm;
#pragma unroll
  for (int mt = 0; mt < 4; ++mt) {
#pragma unroll
    for (int nt = 0; nt < 4; ++nt) {
      int col = (int)col0 + wn + nt * 16 + ln;
      if (vt) {
        long rowb = row0 + wm + mt * 16 + lm4;
        long vbh = rowb >> 10, sx = rowb & 1023;
        f16x4 v;
#pragma unroll
        for (int r = 0; r < 4; ++r) v[r] = (f16)(acc[mt][nt][r] + bias[col]);
        *(f16x4*)&Vt[(vbh * 768 + col) * 1024 + sx] = v;   // Vt[bh][n][s]
      } else {
#pragma unroll
        for (int r = 0; r < 4; ++r) {
          long row = row0 + wm + mt * 16 + lm4 + r;
          float c = acc[mt][nt][r] + bias[col];
          if (col < pelim) {
            int pc = col < 768 ? col : col - 768;
            c += (float)pe[row * 768 + pc];
          }
          outp[row * (long)ldo + col] = (f16)c;
        }
      }
    }
  }
}

// ---------------------------------------------------------------------------
// score128: slab (w,bh): A = QG[bh] cols [w*768..+767] = [q_r|q_i],
// B = Kc[bh] = [k_r|k_i].  s_r = qr.kr + qi.ki ; s_i = qi.kr - qr.ki.
// Merged stage arrays [128][64] f16 (L = chunks 0-3, H = 4-7; 128B rows,
// XOR-8 swizzle -> conflict-free).  BK=32, dbuf (64 KB, 2 blk/CU), counted
// vmcnt(8), 64 MFMA/wave/epoch, 12 epochs.  |s|*scale -> fp16 logits.
// Grid 2048: xcd=bid&7, per=bid>>3; z=xcd*4+per/64 (=w*16+bh); rem=per%64:
// row0=(rem/8)*128, col0=(rem%8)*128.
// ---------------------------------------------------------------------------
__launch_bounds__(256, 2)
__global__ void score128(const f16* __restrict__ QG, const f16* __restrict__ Kc,
                         f16* __restrict__ P)
{
  __shared__ f16 As[2][128 * 64];
  __shared__ f16 Bs[2][128 * 64];
  const int t = threadIdx.x, lane = t & 63, wave = t >> 6;
  const int bid = blockIdx.x;
  const int xcd = bid & 7, per = bid >> 3;
  const int z   = xcd * 4 + per / 64;
  const int rem = per % 64;
  const int w = z >> 4, bh = z & 15;
  const long row0 = (long)(rem / 8) * 128, col0 = (long)(rem % 8) * 128;
  const f16* A = QG + (long)bh * 1024 * 2304 + row0 * 2304 + w * 768;
  const f16* B = Kc + (long)bh * 1024 * 768 + col0 * 768;
  f16* Pz = P + ((long)z << 20);

  const int wm = (wave >> 1) * 64, wn = (wave & 1) * 64;
  const int lm = lane & 15, l4 = lane >> 4;
  f32x4 accr[4][4] = {}, acci[4][4] = {};

  // slot (r,c) holds logical chunk cg=c^(r&7); cg<4 -> L half col kk+cg*8,
  // cg>=4 -> H half col 384+kk+(cg-4)*8.  8 gl2lds/thread/epoch.
  auto stage = [&](int kk, int sub) {
#pragma unroll
    for (int p = 0; p < 4; ++p) {
      int sg = p * 256 + t;                 // 0..1023
      int r = sg >> 3, c = sg & 7, cg = c ^ (r & 7);
      const f16* sa = (cg < 4) ? A + (long)r * 2304 + kk + cg * 8
                               : A + (long)r * 2304 + 384 + kk + (cg - 4) * 8;
      gl2lds16(sa, &As[sub][sg * 8]);
      const f16* sb = (cg < 4) ? B + (long)r * 768 + kk + cg * 8
                               : B + (long)r * 768 + 384 + kk + (cg - 4) * 8;
      gl2lds16(sb, &Bs[sub][sg * 8]);
    }
  };

  stage(0, 0);
  stage(32, 1);
  int cur = 0;
  for (int it = 0; it < 12; ++it) {
    if (it + 1 < 12) asm volatile("s_waitcnt vmcnt(8)" ::: "memory");
    else             asm volatile("s_waitcnt vmcnt(0)" ::: "memory");
    __builtin_amdgcn_s_barrier();
    f16x8 bl[4], bh2[4];
#pragma unroll
    for (int nt = 0; nt < 4; ++nt) {
      int rr = wn + nt * 16 + lm;
      bl[nt]  = *(const f16x8*)&Bs[cur][rr * 64 + ((l4 ^ (rr & 7)) << 3)];
      bh2[nt] = *(const f16x8*)&Bs[cur][rr * 64 + (((l4 + 4) ^ (rr & 7)) << 3)];
    }
#pragma unroll
    for (int mt = 0; mt < 4; ++mt) {
      int rr = wm + mt * 16 + lm;
      f16x8 al  = *(const f16x8*)&As[cur][rr * 64 + ((l4 ^ (rr & 7)) << 3)];
      f16x8 ah  = *(const f16x8*)&As[cur][rr * 64 + (((l4 + 4) ^ (rr & 7)) << 3)];
      f16x8 nal = -al;
#pragma unroll
      for (int nt = 0; nt < 4; ++nt) {
        accr[mt][nt] = __builtin_amdgcn_mfma_f32_16x16x32_f16(al,  bl[nt],  accr[mt][nt], 0, 0, 0);
        accr[mt][nt] = __builtin_amdgcn_mfma_f32_16x16x32_f16(ah,  bh2[nt], accr[mt][nt], 0, 0, 0);
        acci[mt][nt] = __builtin_amdgcn_mfma_f32_16x16x32_f16(ah,  bl[nt],  acci[mt][nt], 0, 0, 0);
        acci[mt][nt] = __builtin_amdgcn_mfma_f32_16x16x32_f16(nal, bh2[nt], acci[mt][nt], 0, 0, 0);
      }
    }
    __builtin_amdgcn_s_barrier();
    if (it + 2 < 12) stage((it + 2) << 5, cur);
    cur ^= 1;
  }
  const int lm4 = l4 * 4, ln = lm;
#pragma unroll
  for (int mt = 0; mt < 4; ++mt)
#pragma unroll
    for (int nt = 0; nt < 4; ++nt) {
      int col = (int)col0 + wn + nt * 16 + ln;
#pragma unroll
      for (int r = 0; r < 4; ++r) {
        long row = row0 + wm + mt * 16 + lm4 + r;
        float sr = accr[mt][nt][r], si = acci[mt][nt][r];
        float m = sqrtf(sr * sr + si * si + 1e-8f) * SCALE_QK;
        Pz[row * 1024 + col] = (f16)m;
      }
    }
}

// In-place row softmax over 1024 logits; 1 wave per row, 4 rows per block.
__global__ void softmax_kernel(f16* __restrict__ P)
{
  const long row = (long)blockIdx.x * 4 + (threadIdx.x >> 6);
  f16* p = P + row * 1024;
  const int lane = threadIdx.x & 63;
  f16x8 v0 = *(const f16x8*)(p + lane * 16);
  f16x8 v1 = *(const f16x8*)(p + lane * 16 + 8);
  float x[16];
#pragma unroll
  for (int i = 0; i < 8; ++i) { x[i] = (float)v0[i]; x[8 + i] = (float)v1[i]; }
  float m = x[0];
#pragma unroll
  for (int i = 1; i < 16; ++i) m = fmaxf(m, x[i]);
#pragma unroll
  for (int off = 1; off < 64; off <<= 1) m = fmaxf(m, __shfl_xor(m, off));
  float s = 0.f;
#pragma unroll
  for (int i = 0; i < 16; ++i) { x[i] = __expf(x[i] - m); s += x[i]; }
#pragma unroll
  for (int off = 1; off < 64; off <<= 1) s += __shfl_xor(s, off);
  float inv = 1.f / s;
  f16x8 o0, o1;
#pragma unroll
  for (int i = 0; i < 8; ++i) { o0[i] = (f16)(x[i] * inv); o1[i] = (f16)(x[8 + i] * inv); }
  *(f16x8*)(p + lane * 16)     = o0;
  *(f16x8*)(p + lane * 16 + 8) = o1;
}

// RMSNorm over cat(a1,a2) + lambda diff + complex gate -> Xatt fp16.
__global__ void fuse_kernel(const f16* __restrict__ A1, const f16* __restrict__ A2,
                            const f16* __restrict__ QG, const float* __restrict__ subw,
                            const float* __restrict__ lamp, f16* __restrict__ Xatt)
{
  const long row = blockIdx.x;
  const int t = threadIdx.x, lane = t & 63, wv = t >> 6;
  const f16* a1 = A1 + row * 768;
  const f16* a2 = A2 + row * 768;
  const f16* g  = QG + row * 2304 + 1536;
  float a1r[3], a1i[3], a2r[3], a2i[3];
  float ss = 0.f;
#pragma unroll
  for (int q = 0; q < 3; ++q) {
    int d = t + q * 128;
    a1r[q] = (float)a1[d]; a1i[q] = (float)a1[d + 384];
    a2r[q] = (float)a2[d]; a2i[q] = (float)a2[d + 384];
    ss += a1r[q] * a1r[q] + a1i[q] * a1i[q] + a2r[q] * a2r[q] + a2i[q] * a2i[q];
  }
#pragma unroll
  for (int m = 1; m < 64; m <<= 1) ss += __shfl_xor(ss, m);
  __shared__ float part[2];
  if (lane == 0) part[wv] = ss;
  __syncthreads();
  float inv = rsqrtf((part[0] + part[1]) * (1.f / 768.f) + 1e-5f);
  float lam = lamp[0];
#pragma unroll
  for (int q = 0; q < 3; ++q) {
    int d = t + q * 128;
    float w1 = subw[d], w2 = subw[d + 384];
    float n1r = a1r[q] * inv * w1, n1i = a1i[q] * inv * w1;
    float n2r = a2r[q] * inv * w2, n2i = a2i[q] * inv * w2;
    float orr = n1r - lam * n2r, oii = n1i - lam * n2i;
    float gr = (float)g[d], gi = (float)g[d + 384];
    Xatt[row * 768 + d]       = (f16)(gr * orr - gi * oii);
    Xatt[row * 768 + d + 384] = (f16)(gr * oii + gi * orr);
  }
}

// ---------------------------------------------------------------------------
// prep_kernel: all weight packs + all x/PE packs + lam scalar, one launch.
// Ranges: [0,6912) wq+wg | [6912,13824) wk/wv/wo | [13824,44544) x-packs
// (q,k,v,peq,pek) | [44544] lam.
// ---------------------------------------------------------------------------
struct PrepArgs {
  const float *wq_r, *wq_i, *wg_r, *wg_i, *bq_r, *bq_i, *bg_r, *bg_i;
  const float *wk_r, *wk_i, *bk_r, *bk_i;
  const float *wv_r, *wv_i, *bv_r, *bv_i;
  const float *wo_r, *wo_i, *bo_r, *bo_i;
  const float *q_r, *q_i, *k_r, *k_i, *v_r, *v_i;
  const float *pe_q_r, *pe_q_i, *pe_k_r, *pe_k_i;
  const float *lq1, *lk1, *lq2, *lk2;
  f16 *Wq, *Wk, *Wv, *Wo;
  float *bq, *bk, *bv, *bo, *lamp;
  f16 *Xq, *Xk, *Xv, *PEQ, *PEK;
};

__global__ void prep_kernel(PrepArgs a)
{
  const int bid = blockIdx.x, t = threadIdx.x;
  __shared__ float p1[4], p2[4];
  if (bid < 6912) {
    // Wq' [2304][768]: 384-row sections 0:q1_r 1:q1_i 2:q2_r 3:q2_i 4:g_r 5:g_i
    long i = (long)bid * 256 + t;
    int n = (int)(i / 768), e = (int)(i % 768);
    int s = n / 384, d = n - s * 384;
    int hb = (e >= 384);
    int ee = e - hb * 384;
    float v = 0.f, b = 0.f;
    switch (s) {
      case 0: v = hb ? -a.wq_i[d * 384 + ee]         :  a.wq_r[d * 384 + ee];         b = a.bq_r[d];       break;
      case 1: v = hb ?  a.wq_r[d * 384 + ee]         :  a.wq_i[d * 384 + ee];         b = a.bq_i[d];       break;
      case 2: v = hb ? -a.wq_i[(384 + d) * 384 + ee] :  a.wq_r[(384 + d) * 384 + ee]; b = a.bq_r[384 + d]; break;
      case 3: v = hb ?  a.wq_r[(384 + d) * 384 + ee] :  a.wq_i[(384 + d) * 384 + ee]; b = a.bq_i[384 + d]; break;
      case 4: v = hb ? -a.wg_i[d * 384 + ee]         :  a.wg_r[d * 384 + ee];         b = a.bg_r[d];       break;
      case 5: v = hb ?  a.wg_r[d * 384 + ee]         :  a.wg_i[d * 384 + ee];         b = a.bg_i[d];       break;
    }
    a.Wq[i] = (f16)v;
    if (e == 0) a.bq[n] = b;
  } else if (bid < 13824) {
    int sel = (bid - 6912) / 2304, lb = (bid - 6912) % 2304;
    const float *wr, *wi, *br, *bi; f16* Wp; float* bp;
    if (sel == 0)      { wr = a.wk_r; wi = a.wk_i; br = a.bk_r; bi = a.bk_i; Wp = a.Wk; bp = a.bk; }
    else if (sel == 1) { wr = a.wv_r; wi = a.wv_i; br = a.bv_r; bi = a.bv_i; Wp = a.Wv; bp = a.bv; }
    else               { wr = a.wo_r; wi = a.wo_i; br = a.bo_r; bi = a.bo_i; Wp = a.Wo; bp = a.bo; }
    long i = (long)lb * 256 + t;
    int n = (int)(i / 768), e = (int)(i % 768);
    int hb = (e >= 384);
    int ee = e - hb * 384;
    float v, b;
    if (n < 384) { v = hb ? -wi[n * 384 + ee] : wr[n * 384 + ee]; b = br[n]; }
    else { int d = n - 384; v = hb ? wr[d * 384 + ee] : wi[d * 384 + ee]; b = bi[d]; }
    Wp[i] = (f16)v;
    if (e == 0) bp[n] = b;
  } else if (bid < 44544) {
    int sel = (bid - 13824) / 6144, lb = (bid - 13824) % 6144;
    const float *xr, *xi; f16* X;
    switch (sel) {
      case 0: xr = a.q_r;    xi = a.q_i;    X = a.Xq;  break;
      case 1: xr = a.k_r;    xi = a.k_i;    X = a.Xk;  break;
      case 2: xr = a.v_r;    xi = a.v_i;    X = a.Xv;  break;
      case 3: xr = a.pe_q_r; xi = a.pe_q_i; X = a.PEQ; break;
      default: xr = a.pe_k_r; xi = a.pe_k_i; X = a.PEK; break;
    }
    long i = (long)lb * 256 + t;
    long row = i / 96;
    int  rem = (int)(i - row * 96);
    int  c   = rem * 8;
    const float* src = (c < 384) ? (xr + row * 384 + c) : (xi + row * 384 + (c - 384));
    f16x8 o;
#pragma unroll
    for (int j = 0; j < 8; ++j) o[j] = (f16)src[j];
    *(f16x8*)&X[row * 768 + c] = o;
  } else {
    // lam scalar
    const int lane = t & 63, wv = t >> 6;
    float s1 = 0.f, s2 = 0.f;
    if (t < 128) {
#pragma unroll
      for (int q = 0; q < 3; ++q) {
        int d = t + q * 128;
        s1 += a.lq1[d] * a.lk1[d];
        s2 += a.lq2[d] * a.lk2[d];
      }
    }
#pragma unroll
    for (int m = 1; m < 64; m <<= 1) { s1 += __shfl_xor(s1, m); s2 += __shfl_xor(s2, m); }
    if (lane == 0) { p1[wv] = s1; p2[wv] = s2; }
    __syncthreads();
    if (t == 0) {
      float x = expf(p1[0] + p1[1] + p1[2] + p1[3]) - expf(p2[0] + p2[1] + p2[2] + p2[3]) + LAMBDA_INIT;
      a.lamp[0] = 1.f / (1.f + expf(-x));
    }
  }
}

// ---------------------------------------------------------------------------
extern "C" void kernel_launch(void* const* d_in, const int* in_sizes, int n_in,
                              void* d_out, int out_size, void* d_ws, size_t ws_size,
                              hipStream_t stream)
{
  const float* subln_w = (const float*)d_in[34];

  char* base = (char*)d_ws;
  size_t off = 0;
  auto alloc = [&](size_t bytes) -> void* {
    void* p = base + off;
    off = (off + bytes + 255) & ~(size_t)255;
    return p;
  };
  f16*   Wq   = (f16*)alloc(2304L * 768 * 2);
  f16*   Wk   = (f16*)alloc(768L * 768 * 2);
  f16*   Wv   = (f16*)alloc(768L * 768 * 2);
  f16*   Wo   = (f16*)alloc(768L * 768 * 2);
  float* bq   = (float*)alloc(2304 * 4);
  float* bk   = (float*)alloc(768 * 4);
  float* bv   = (float*)alloc(768 * 4);
  float* bo   = (float*)alloc(768 * 4);
  float* lamp = (float*)alloc(4);
  f16*   X    = (f16*)alloc(NROW * 768 * 2);    // Xq
  f16*   QG   = (f16*)alloc(NROW * 2304 * 2);   // [q1|q2|g] per row
  f16*   Kc   = (f16*)alloc(NROW * 768 * 2);
  f16*   Vt   = (f16*)alloc(16L * 768 * 1024 * 2);
  f16*   P    = (f16*)alloc(32L * 1024 * 1024 * 2);
  if (off > ws_size) return;
  // overlays:
  f16* A1   = Kc;                       // dead after score
  f16* A2   = X;                        // (Xq) dead after proj
  f16* Xatt = Vt;                       // dead after pv
  f16* PEQ  = P;                        // P not live until score
  f16* PEK  = P + NROW * 768;
  f16* Xk   = (f16*)d_out;              // d_out scratch: dead until out-proj
  f16* Xv   = Xk + NROW * 768;          // 24..48MB of 50.3MB

  PrepArgs pa;
  pa.wq_r = (const float*)d_in[10]; pa.wq_i = (const float*)d_in[11];
  pa.wg_r = (const float*)d_in[22]; pa.wg_i = (const float*)d_in[23];
  pa.bq_r = (const float*)d_in[12]; pa.bq_i = (const float*)d_in[13];
  pa.bg_r = (const float*)d_in[24]; pa.bg_i = (const float*)d_in[25];
  pa.wk_r = (const float*)d_in[14]; pa.wk_i = (const float*)d_in[15];
  pa.bk_r = (const float*)d_in[16]; pa.bk_i = (const float*)d_in[17];
  pa.wv_r = (const float*)d_in[18]; pa.wv_i = (const float*)d_in[19];
  pa.bv_r = (const float*)d_in[20]; pa.bv_i = (const float*)d_in[21];
  pa.wo_r = (const float*)d_in[26]; pa.wo_i = (const float*)d_in[27];
  pa.bo_r = (const float*)d_in[28]; pa.bo_i = (const float*)d_in[29];
  pa.q_r = (const float*)d_in[0]; pa.q_i = (const float*)d_in[1];
  pa.k_r = (const float*)d_in[2]; pa.k_i = (const float*)d_in[3];
  pa.v_r = (const float*)d_in[4]; pa.v_i = (const float*)d_in[5];
  pa.pe_q_r = (const float*)d_in[6]; pa.pe_q_i = (const float*)d_in[7];
  pa.pe_k_r = (const float*)d_in[8]; pa.pe_k_i = (const float*)d_in[9];
  pa.lq1 = (const float*)d_in[30]; pa.lk1 = (const float*)d_in[31];
  pa.lq2 = (const float*)d_in[32]; pa.lk2 = (const float*)d_in[33];
  pa.Wq = Wq; pa.Wk = Wk; pa.Wv = Wv; pa.Wo = Wo;
  pa.bq = bq; pa.bk = bk; pa.bv = bv; pa.bo = bo; pa.lamp = lamp;
  pa.Xq = X; pa.Xk = Xk; pa.Xv = Xv; pa.PEQ = PEQ; pa.PEK = PEK;

  // 1) all packing + lam
  prep_kernel<<<44545, 256, 0, stream>>>(pa);

  // 2) QG + K + V projections
  proj_all<<<3840, 256, 0, stream>>>(X, Xk, Xv, Wq, Wk, Wv, bq, bk, bv,
                                     PEQ, PEK, QG, Kc, Vt);

  // 3) attention
  score128<<<2048, 256, 0, stream>>>(QG, Kc, P);
  softmax_kernel<<<8192, 256, 0, stream>>>(P);
  gemm128<MODE_PV><<<1536, 256, 0, stream>>>(
      P, 1024, Vt, 1024, nullptr, nullptr, 0, A1, A2, 0, 1024, 0);

  // 4) norm + diff + gate
  fuse_kernel<<<16384, 128, 0, stream>>>(A1, A2, QG, subln_w, lamp, Xatt);

  // 5) output projection (overwrites d_out scratch)
  gemm128<MODE_OUT><<<768, 256, 0, stream>>>(
      Xatt, 768, Wo, 768, bo, nullptr, 0, d_out, nullptr, 0, 768, 6);

  (void)in_sizes; (void)n_in; (void)out_size;
}